// Round 10
// baseline (6557.549 us; speedup 1.0000x reference)
//
#include <hip/hip_runtime.h>

#define DEV __device__ __forceinline__

typedef _Float16 half8 __attribute__((ext_vector_type(8)));
typedef float f32x4 __attribute__((ext_vector_type(4)));

DEV void gload_lds16(const void* g, void* l) {
  __builtin_amdgcn_global_load_lds(
      (const __attribute__((address_space(1))) void*)g,
      (__attribute__((address_space(3))) void*)l, 16, 0, 0);
}

DEV float sigmoidf_(float x) { return 1.f / (1.f + __expf(-x)); }
DEV float tanh_fast(float x) { return 1.f - 2.f / (__expf(2.f * x) + 1.f); }

// Device-scope grid barrier: monotonic counter, sense-free. All 512 blocks
// are co-resident (launch_bounds(256,2), grid=2*256CU), so arrive+spin is
// deadlock-free; spin is bounded so a residency bug shows as wrong output,
// not a hang. __threadfence() (device scope) provides cross-XCD L2 WB/INV.
DEV void gbar(unsigned* cnt, unsigned target) {
  __syncthreads();
  __threadfence();
  if (threadIdx.x == 0) {
    __hip_atomic_fetch_add(cnt, 1u, __ATOMIC_RELEASE, __HIP_MEMORY_SCOPE_AGENT);
    int spins = 0;
    while (__hip_atomic_load(cnt, __ATOMIC_ACQUIRE, __HIP_MEMORY_SCOPE_AGENT) <
               target &&
           ++spins < (1 << 22)) {
    }
  }
  __syncthreads();
  __threadfence();
}

__global__ void init_bar(unsigned* cnt) {
  if (threadIdx.x == 0)
    __hip_atomic_store(cnt, 0u, __ATOMIC_RELEASE, __HIP_MEMORY_SCOPE_AGENT);
}

struct ChainArgs {
  const _Float16* z_h;
  const _Float16* WzT;
  const _Float16* W12T;
  const _Float16* W3T;
  const _Float16* WoT;
  const float *bz, *b1, *b2, *b3, *bo;
  _Float16* cat;     // [4096][1536] = [s' | x]
  _Float16* cat2;    // [4096][1536] = [r*s' | x]
  _Float16* u_h;     // [4096][1024]
  _Float16* st_h;    // [4096][1024]
  _Float16* belta;   // [11][4096][1024] (slice j <-> step t=j+1)
  float* out;        // [4096][12][512]
  unsigned* bar;     // grid-barrier counter
};

// One GEMM phase of the persistent chain. 128xBN tile, BK=32, 4 waves (2x2).
// Staging LDS: 16B slots; logical (row m, k-group g) at slot m*4+(g^((m>>1)&3));
// inverse perm applied on the GLOBAL src addr so global_load_lds dest is linear.
// Epilogue: acc -> f16 tile in LDS (aliased, barrier-separated) -> half8 I/O.
// Koff: skip A/B K-range [0,Koff) (t=0: s'==0 contributes nothing).
template <int BN>
DEV void gemm_phase(char* smem, const _Float16* A, int lda,
                    const _Float16* BT, int ldb, int K, int Koff,
                    int ntiles, int XC, int RM, int RN, int epi, int t,
                    const float* bias, const float* bias2, const ChainArgs& a) {
  const int bid = blockIdx.x;
  if (bid >= ntiles) return;  // idle blocks fall through to the grid barrier
  constexpr int NJ = BN / 32;
  _Float16* As = (_Float16*)smem;          // 128*32 f16 = 8 KB
  _Float16* Bs = As + 4096;                // BN*32 f16
  _Float16* Cs = (_Float16*)smem;          // aliased; barrier-separated

  const int tid = threadIdx.x;
  const int lane = tid & 63;
  const int wave = tid >> 6;

  // XCD-aware bijective tile map: tile grid (8/XC*RM) x (XC*RN)
  const int xcd = bid & 7;
  const int kk = bid >> 3;
  const int tm = (xcd / XC) * RM + kk / RN;
  const int tn = (xcd % XC) * RN + kk % RN;
  const int bm = tm * 128;
  const int bn = tn * BN;

  const int wm = (wave >> 1) * 64;
  const int wn = (wave & 1) * (BN / 2);
  const int fr = lane & 15;  // frag row (A) / col (B)
  const int fg = lane >> 4;  // k-group 0..3

  const int d2 = lane >> 2, d3 = lane & 3;
  const int m0 = wave * 16 + d2;
  const int m1 = (wave + 4) * 16 + d2;
  const int g0 = d3 ^ ((m0 >> 1) & 3);
  const int g1 = d3 ^ ((m1 >> 1) & 3);

  const _Float16* gB0 = BT + (size_t)(bn + m0) * ldb + Koff + g0 * 8;
  const _Float16* gB1 = BT + (size_t)(bn + m1) * ldb + Koff + g1 * 8;
  const _Float16* gA0 = A + (size_t)(bm + m0) * lda + Koff + g0 * 8;
  const _Float16* gA1 = A + (size_t)(bm + m1) * lda + Koff + g1 * 8;

  const f32x4 zv = {0.f, 0.f, 0.f, 0.f};
  f32x4 acc[4][NJ];
#pragma unroll
  for (int i = 0; i < 4; ++i)
#pragma unroll
    for (int j = 0; j < NJ; ++j) acc[i][j] = zv;

  for (int k0 = 0; k0 < K; k0 += 32) {
    if (k0) __syncthreads();
    gload_lds16(gB0, Bs + wave * 512);
    gB0 += 32;
    if constexpr (BN == 128) {
      gload_lds16(gB1, Bs + (wave + 4) * 512);
      gB1 += 32;
    }
    gload_lds16(gA0, As + wave * 512);
    gA0 += 32;
    gload_lds16(gA1, As + (wave + 4) * 512);
    gA1 += 32;
    __syncthreads();

    half8 af[4], bf[NJ];
#pragma unroll
    for (int i = 0; i < 4; ++i) {
      int am = wm + i * 16 + fr;
      af[i] = *(const half8*)(As + (size_t)(am * 4 + (fg ^ ((am >> 1) & 3))) * 8);
    }
#pragma unroll
    for (int j = 0; j < NJ; ++j) {
      int bb = wn + j * 16 + fr;
      bf[j] = *(const half8*)(Bs + (size_t)(bb * 4 + (fg ^ ((bb >> 1) & 3))) * 8);
    }
#pragma unroll
    for (int i = 0; i < 4; ++i)
#pragma unroll
      for (int j = 0; j < NJ; ++j)
        acc[i][j] =
            __builtin_amdgcn_mfma_f32_16x16x32_f16(af[i], bf[j], acc[i][j], 0, 0, 0);
  }

  // epilogue phase 1: activation on f32 acc -> f16 tile in LDS
  // C/D layout (gfx950): col = lane&15, row = (lane>>4)*4 + reg
  __syncthreads();
  const int row0l = wm + fg * 4;
  const int col0l = wn + fr;
#pragma unroll
  for (int i = 0; i < 4; ++i) {
#pragma unroll
    for (int j = 0; j < NJ; ++j) {
      const int cl = col0l + j * 16;
      const int col = bn + cl;
      const float bv = (epi == 2 && col >= 1024) ? bias2[col - 1024] : bias[col];
#pragma unroll
      for (int r = 0; r < 4; ++r) {
        const int rl = row0l + i * 16 + r;
        float v = acc[i][j][r] + bv;
        float val;
        if (epi == 2) val = sigmoidf_(v);
        else if (epi == 3) val = tanh_fast(v);
        else val = v;
        Cs[rl * BN + cl] = (_Float16)val;
      }
    }
  }
  __syncthreads();

  // epilogue phase 2: vectorized half8 global traffic
  constexpr int CPR = BN / 8;
#pragma unroll
  for (int c = tid; c < 128 * CPR; c += 256) {
    const int row = c / CPR;
    const int off8 = (c % CPR) * 8;
    const int rg = bm + row;
    half8 hv = *(const half8*)(Cs + row * BN + off8);
    if (epi == 0 || epi == 4) {  // x-part of cat, cat2 (+ f32 out for epi4)
      *(half8*)(a.cat + (size_t)rg * 1536 + 1024 + bn + off8) = hv;
      *(half8*)(a.cat2 + (size_t)rg * 1536 + 1024 + bn + off8) = hv;
      if (epi == 4) {
        float* op = a.out + ((size_t)rg * 12 + t) * 512 + bn + off8;
        float4 f0, f1;
        f0.x = (float)hv[0]; f0.y = (float)hv[1];
        f0.z = (float)hv[2]; f0.w = (float)hv[3];
        f1.x = (float)hv[4]; f1.y = (float)hv[5];
        f1.z = (float)hv[6]; f1.w = (float)hv[7];
        *(float4*)op = f0;
        *(float4*)(op + 4) = f1;
      }
    } else if (epi == 2) {
      if (bn < 1024) {  // u
        *(half8*)(a.u_h + (size_t)rg * 1024 + bn + off8) = hv;
      } else {  // cat2 state-part = r * s'   (t=0: s'=0)
        const int cc = bn - 1024 + off8;
        half8 o;
        if (t == 0) {
#pragma unroll
          for (int e = 0; e < 8; ++e) o[e] = (_Float16)0;
        } else {
          half8 sp = *(const half8*)(a.cat + (size_t)rg * 1536 + cc);
#pragma unroll
          for (int e = 0; e < 8; ++e)
            o[e] = (_Float16)((float)hv[e] * (float)sp[e]);
        }
        *(half8*)(a.cat2 + (size_t)rg * 1536 + cc) = o;
      }
    } else {  // epi 3: state = (1-u)s' + u*tanh; s'_{t+1} = belta_{t+1}*state
      half8 uu = *(const half8*)(a.u_h + (size_t)rg * 1024 + bn + off8);
      half8 st;
      if (t == 0) {
#pragma unroll
        for (int e = 0; e < 8; ++e)
          st[e] = (_Float16)((float)uu[e] * (float)hv[e]);
      } else {
        half8 sp = *(const half8*)(a.cat + (size_t)rg * 1536 + bn + off8);
#pragma unroll
        for (int e = 0; e < 8; ++e) {
          float u = (float)uu[e];
          st[e] = (_Float16)((1.f - u) * (float)sp[e] + u * (float)hv[e]);
        }
      }
      *(half8*)(a.st_h + (size_t)rg * 1024 + bn + off8) = st;
      if (t < 11) {
        half8 bl = *(const half8*)(a.belta + (size_t)t * 4194304 +
                                   (size_t)rg * 1024 + bn + off8);
        half8 ns;
#pragma unroll
        for (int e = 0; e < 8; ++e)
          ns[e] = (_Float16)((float)bl[e] * (float)st[e]);
        *(half8*)(a.cat + (size_t)rg * 1536 + bn + off8) = ns;
      }
    }
  }
}

// Persistent chain: EPI0 + 12 x (EPI2 -> EPI3 -> EPI4), normal launch,
// hand-rolled grid barrier. 512 blocks x 256 threads; launch_bounds(256,2)
// guarantees >=2 blocks/CU so all 512 blocks are co-resident on 256 CUs.
__global__ __launch_bounds__(256, 2) void chain_kernel(ChainArgs a) {
  __shared__ __align__(16) char smem[32768];
  unsigned ph = 0;
  // x = z@Wz + bz  (4096x512, K=128): 32x8 tiles
  gemm_phase<64>(smem, a.z_h, 128, a.WzT, 128, 128, 0, 256, 2, 8, 4,
                 0, 0, a.bz, nullptr, a);
  gbar(a.bar, ++ph * 512);
#pragma unroll 1
  for (int t = 0; t < 12; ++t) {
    const int K = t ? 1536 : 512;
    const int Ko = t ? 0 : 1024;
    // [u|r] = sigmoid(cat@[W1|W2]); cat2 s'-part = r*s'  (32x16 tiles, BN=128)
    gemm_phase<128>(smem, a.cat, 1536, a.W12T, 1536, K, Ko, 512, 2, 8, 8,
                    2, t, a.b1, a.b2, a);
    gbar(a.bar, ++ph * 512);
    // state = (1-u)s' + u*tanh(cat2@W3); s'_{t+1} = belta*state (32x16, BN=64)
    gemm_phase<64>(smem, a.cat2, 1536, a.W3T, 1536, K, Ko, 512, 2, 8, 8,
                   3, t, a.b3, nullptr, a);
    gbar(a.bar, ++ph * 512);
    // out_t = state@Wout + bo -> d_out, next x  (32x8 tiles, BN=64)
    gemm_phase<64>(smem, a.st_h, 1024, a.WoT, 1024, 1024, 0, 256, 2, 8, 4,
                   4, t, a.bo, nullptr, a);
    gbar(a.bar, ++ph * 512);
  }
}

// belta = exp(-relu(td@Wb + bb)) for t=1..11, one parallel GEMM
// M=45056, N=1024, K=512; 128x128 tiles, grid 352x8 = 2816.
struct BArgs {
  const _Float16* td_h;  // [4096][12][512]
  const _Float16* WbT;   // [1024][512]
  const float* bb;
  _Float16* belta;       // [11][4096][1024]
};
__global__ __launch_bounds__(256) void belta_gemm(BArgs g) {
  __shared__ __align__(16) char smem[32768];
  _Float16* As = (_Float16*)smem;
  _Float16* Bs = As + 4096;
  _Float16* Cs = (_Float16*)smem;
  const int tid = threadIdx.x;
  const int lane = tid & 63;
  const int wave = tid >> 6;
  const int bid = blockIdx.x;
  const int xcd = bid & 7;
  const int kk = bid >> 3;
  const int tm = xcd * 44 + kk / 8;   // XC=1, RM=44, RN=8
  const int tn = kk % 8;
  const int bn = tn * 128;
  const int t = (tm >> 5) + 1;
  const size_t rb = (size_t)(tm & 31) * 128;

  const int wm = (wave >> 1) * 64;
  const int wn = (wave & 1) * 64;
  const int fr = lane & 15;
  const int fg = lane >> 4;
  const int d2 = lane >> 2, d3 = lane & 3;
  const int m0 = wave * 16 + d2;
  const int m1 = (wave + 4) * 16 + d2;
  const int g0 = d3 ^ ((m0 >> 1) & 3);
  const int g1 = d3 ^ ((m1 >> 1) & 3);

  const _Float16* gB0 = g.WbT + (size_t)(bn + m0) * 512 + g0 * 8;
  const _Float16* gB1 = g.WbT + (size_t)(bn + m1) * 512 + g1 * 8;
  const _Float16* gA0 = g.td_h + (rb + m0) * 6144 + t * 512 + g0 * 8;
  const _Float16* gA1 = g.td_h + (rb + m1) * 6144 + t * 512 + g1 * 8;

  const f32x4 zv = {0.f, 0.f, 0.f, 0.f};
  f32x4 acc[4][4];
#pragma unroll
  for (int i = 0; i < 4; ++i)
#pragma unroll
    for (int j = 0; j < 4; ++j) acc[i][j] = zv;

  for (int k0 = 0; k0 < 512; k0 += 32) {
    if (k0) __syncthreads();
    gload_lds16(gB0, Bs + wave * 512);
    gload_lds16(gB1, Bs + (wave + 4) * 512);
    gB0 += 32; gB1 += 32;
    gload_lds16(gA0, As + wave * 512);
    gload_lds16(gA1, As + (wave + 4) * 512);
    gA0 += 32; gA1 += 32;
    __syncthreads();

    half8 af[4], bf[4];
#pragma unroll
    for (int i = 0; i < 4; ++i) {
      int am = wm + i * 16 + fr;
      af[i] = *(const half8*)(As + (size_t)(am * 4 + (fg ^ ((am >> 1) & 3))) * 8);
      int bb2 = wn + i * 16 + fr;
      bf[i] = *(const half8*)(Bs + (size_t)(bb2 * 4 + (fg ^ ((bb2 >> 1) & 3))) * 8);
    }
#pragma unroll
    for (int i = 0; i < 4; ++i)
#pragma unroll
      for (int j = 0; j < 4; ++j)
        acc[i][j] =
            __builtin_amdgcn_mfma_f32_16x16x32_f16(af[i], bf[j], acc[i][j], 0, 0, 0);
  }

  __syncthreads();
  const int row0l = wm + fg * 4;
  const int col0l = wn + fr;
#pragma unroll
  for (int i = 0; i < 4; ++i)
#pragma unroll
    for (int j = 0; j < 4; ++j) {
      const int cl = col0l + j * 16;
      const float bv = g.bb[bn + cl];
#pragma unroll
      for (int r = 0; r < 4; ++r)
        Cs[(row0l + i * 16 + r) * 128 + cl] =
            (_Float16)__expf(-fmaxf(0.f, acc[i][j][r] + bv));
    }
  __syncthreads();
#pragma unroll
  for (int c = tid; c < 128 * 16; c += 256) {
    const int row = c >> 4;
    const int off8 = (c & 15) * 8;
    *(half8*)(g.belta + ((size_t)tm * 128 + row) * 1024 + bn + off8) =
        *(const half8*)(Cs + row * 128 + off8);
  }
}

// fused weight transposes: f32 [K][N] -> f16 [N][K] via 32x33 LDS tile
struct TSeg { const float* src; _Float16* dst; int K, N, cnt, nbx; };
struct TAll { TSeg s[6]; };
__global__ __launch_bounds__(256) void transpose_all(TAll a) {
  int b = blockIdx.x, s = 0;
  while (s < 5 && b >= a.s[s].cnt) { b -= a.s[s].cnt; ++s; }
  const float* src = a.s[s].src;
  _Float16* dst = a.s[s].dst;
  const int K = a.s[s].K, N = a.s[s].N, nbx = a.s[s].nbx;
  const int nb = (b % nbx) * 32, kb = (b / nbx) * 32;
  __shared__ float tile[32][33];
  const int tx = threadIdx.x & 31, ty = threadIdx.x >> 5;
#pragma unroll
  for (int i = ty; i < 32; i += 8)
    tile[i][tx] = src[(size_t)(kb + i) * N + nb + tx];
  __syncthreads();
#pragma unroll
  for (int i = ty; i < 32; i += 8)
    dst[(size_t)(nb + i) * K + kb + tx] = (_Float16)tile[tx][i];
}

// fused f32->f16 convert: td (12288 blocks) then z (256 blocks)
__global__ __launch_bounds__(256) void cvt_all(const float* __restrict__ td,
                                               const float* __restrict__ z,
                                               _Float16* __restrict__ td_h,
                                               _Float16* __restrict__ z_h) {
  const int b = blockIdx.x;
  const float* src;
  _Float16* dst;
  size_t idx;
  if (b < 12288) { src = td; dst = td_h; idx = (size_t)b * 256 + threadIdx.x; }
  else { src = z; dst = z_h; idx = (size_t)(b - 12288) * 256 + threadIdx.x; }
  const float4* p = (const float4*)(src + idx * 8);
  float4 va = p[0], vb = p[1];
  half8 h;
  h[0] = (_Float16)va.x; h[1] = (_Float16)va.y;
  h[2] = (_Float16)va.z; h[3] = (_Float16)va.w;
  h[4] = (_Float16)vb.x; h[5] = (_Float16)vb.y;
  h[6] = (_Float16)vb.z; h[7] = (_Float16)vb.w;
  *(half8*)(dst + idx * 8) = h;
}

extern "C" void kernel_launch(void* const* d_in, const int* in_sizes, int n_in,
                              void* d_out, int out_size, void* d_ws,
                              size_t ws_size, hipStream_t stream) {
  const float* z  = (const float*)d_in[0];
  const float* td = (const float*)d_in[1];
  const float* Wb = (const float*)d_in[2];
  const float* bb = (const float*)d_in[3];
  const float* Wz = (const float*)d_in[4];
  const float* bz = (const float*)d_in[5];
  const float* W1 = (const float*)d_in[6];
  const float* b1 = (const float*)d_in[7];
  const float* W2 = (const float*)d_in[8];
  const float* b2 = (const float*)d_in[9];
  const float* W3 = (const float*)d_in[10];
  const float* b3 = (const float*)d_in[11];
  const float* Wo = (const float*)d_in[12];
  const float* bo = (const float*)d_in[13];
  float* out = (float*)d_out;

  char* ws = (char*)d_ws;
  size_t off = 0;
  auto alloc = [&](size_t bytes) {
    void* p = ws + off;
    off += (bytes + 255) & ~(size_t)255;
    return p;
  };
  _Float16* WzT  = (_Float16*)alloc((size_t)512 * 128 * 2);
  _Float16* WbT  = (_Float16*)alloc((size_t)1024 * 512 * 2);
  _Float16* W12T = (_Float16*)alloc((size_t)2048 * 1536 * 2);
  _Float16* W3T  = (_Float16*)alloc((size_t)1024 * 1536 * 2);
  _Float16* WoT  = (_Float16*)alloc((size_t)512 * 1024 * 2);
  _Float16* z_h  = (_Float16*)alloc((size_t)4096 * 128 * 2);
  _Float16* td_h = (_Float16*)alloc((size_t)4096 * 12 * 512 * 2);
  _Float16* cat  = (_Float16*)alloc((size_t)4096 * 1536 * 2);
  _Float16* cat2 = (_Float16*)alloc((size_t)4096 * 1536 * 2);
  _Float16* u_h  = (_Float16*)alloc((size_t)4096 * 1024 * 2);
  _Float16* st_h = (_Float16*)alloc((size_t)4096 * 1024 * 2);
  _Float16* beltaA = (_Float16*)alloc((size_t)11 * 4096 * 1024 * 2);
  unsigned* bar = (unsigned*)alloc(256);
  if (off > ws_size) return;  // not enough scratch: fail cleanly

  dim3 blk(256);

  // prologue: weight transposes + converts + barrier init
  TAll ta;
  ta.s[0] = {Wz, WzT, 128, 512, (128 / 32) * (512 / 32), 512 / 32};
  ta.s[1] = {Wb, WbT, 512, 1024, (512 / 32) * (1024 / 32), 1024 / 32};
  ta.s[2] = {W1, W12T, 1536, 1024, (1536 / 32) * (1024 / 32), 1024 / 32};
  ta.s[3] = {W2, W12T + (size_t)1024 * 1536, 1536, 1024,
             (1536 / 32) * (1024 / 32), 1024 / 32};
  ta.s[4] = {W3, W3T, 1536, 1024, (1536 / 32) * (1024 / 32), 1024 / 32};
  ta.s[5] = {Wo, WoT, 1024, 512, (1024 / 32) * (512 / 32), 512 / 32};
  int ttot = 0;
  for (int i = 0; i < 6; ++i) ttot += ta.s[i].cnt;
  init_bar<<<1, 64, 0, stream>>>(bar);
  transpose_all<<<ttot, blk, 0, stream>>>(ta);
  cvt_all<<<12288 + 256, blk, 0, stream>>>(td, z, td_h, z_h);

  // belta for t=1..11 (parallel in t)
  BArgs ba{td_h, WbT, bb, beltaA};
  belta_gemm<<<2816, blk, 0, stream>>>(ba);

  // the recurrence: one persistent kernel with hand-rolled grid barriers
  ChainArgs ca;
  ca.z_h = z_h; ca.WzT = WzT; ca.W12T = W12T; ca.W3T = W3T; ca.WoT = WoT;
  ca.bz = bz; ca.b1 = b1; ca.b2 = b2; ca.b3 = b3; ca.bo = bo;
  ca.cat = cat; ca.cat2 = cat2; ca.u_h = u_h; ca.st_h = st_h;
  ca.belta = beltaA; ca.out = out; ca.bar = bar;
  chain_kernel<<<512, blk, 0, stream>>>(ca);
}